// Round 9
// baseline (205.075 us; speedup 1.0000x reference)
//
#include <hip/hip_runtime.h>
#include <stdint.h>

typedef __attribute__((ext_vector_type(8))) short          s16x8;
typedef __attribute__((ext_vector_type(8))) unsigned short u16x8;
typedef __attribute__((ext_vector_type(4))) float          f32x4;

#define HWPIX 9216
#define OUTSZ 1179648
#define OSTR  68            // padded hbuf/outr row stride (f32)
#define ABLK  10240         // u16 per block's A-frag region: 5ks*4mi*64lane*8
#define BJB   40960         // u16 per jb's B-frag region: 5ks*4wid*4ni*64lane*8

static __device__ __forceinline__ unsigned short f2bf(float f) {
  unsigned int u = __float_as_uint(f);
  u += 0x7fffu + ((u >> 16) & 1u);
  return (unsigned short)(u >> 16);
}

// ---------------------------------------------------------------------------
// prep: A and B in FRAGMENT-LINEAR order (consumer lane l reads base + l*16B).
// A-frag: [bx(288)][ks(5)][mi(4)][lane(64)][8 u16]
//   row = bx*64 + mi*16 + (lane&15) (= p*2+n2), k = ks*32 + (lane>>4)*8 + t
// B-frag: [jb(17)][ks(5)][wid(4)][ni(4)][lane(64)][8 u16]
//   col = jb*256 + wid*64 + ni*16 + (lane&15) (col<4096: j*16+c),
//   k   = ks*32 + (lane>>4)*8 + t
//   jb==16 = bias block: col 4096+c for jl==0 -> b2[k*16+c], else 0.
// ---------------------------------------------------------------------------
__global__ __launch_bounds__(256)
void ml_prep(const float* __restrict__ x, const float* __restrict__ w2,
             const float* __restrict__ b2,
             unsigned short* __restrict__ Afrag, unsigned short* __restrict__ Bfrag)
{
  int idx = blockIdx.x * 256 + threadIdx.x;
  if (idx < 368640) {                      // A: 288 blocks x 1280 u16x8 units
    int bx = idx / 1280, r = idx - bx * 1280;
    int ks = r >> 8, mi = (r >> 6) & 3, lane = r & 63;
    int row = bx * 64 + mi * 16 + (lane & 15);
    int p = row >> 1, n2 = row & 1;
    int hh = p / 96, ww = p - hh * 96;
    int k0 = ks * 32 + (lane >> 4) * 8;
    u16x8 v;
#pragma unroll
    for (int t = 0; t < 8; t++) {
      int k = k0 + t;
      float xv = 0.f;
      if (k < 144) {
        int cc = k / 9, kidx = k - cc * 9;
        int ih = hh + kidx / 3 - 1, iw = ww + (kidx % 3) - 1;
        if (ih >= 0 && ih < 96 && iw >= 0 && iw < 96)
          xv = x[((n2 * 16 + cc) * 96 + ih) * 96 + iw];
      }
      v[t] = f2bf(xv);
    }
    *(u16x8*)(Afrag + (size_t)idx * 8) = v;
    return;
  }
  idx -= 368640;
  if (idx < 87040) {                       // B: 17jb*5ks*4wid*4ni*64lane units
    int lane = idx & 63;
    int u  = idx >> 6;
    int ni = u & 3;
    int u2 = u >> 2;
    int wid = u2 & 3;
    int u3 = u2 >> 2;
    int ks = u3 % 5;
    int jb = u3 / 5;
    int col = jb * 256 + wid * 64 + ni * 16 + (lane & 15);
    int k0 = ks * 32 + (lane >> 4) * 8;
    u16x8 v;
    if (col < 4096) {
      int j = col >> 4, c = col & 15;
#pragma unroll
      for (int t = 0; t < 8; t++) {
        int k = k0 + t;
        v[t] = (k < 144) ? f2bf(w2[j * 2304 + k * 16 + c]) : (unsigned short)0;
      }
    } else {
      int m = col - 4096;
      int jl = m >> 4, c = m & 15;
#pragma unroll
      for (int t = 0; t < 8; t++) {
        int k = k0 + t;
        v[t] = (jl == 0 && k < 144) ? f2bf(b2[k * 16 + c]) : (unsigned short)0;
      }
    }
    *(u16x8*)(Bfrag + (size_t)idx * 8) = v;
  }
}

// ---------------------------------------------------------------------------
// main: grid (288, 2), 256 threads (4 waves). Block = 64 M-rows x j-half.
//   jy=0: jb 0..8 ; jy=1: jb 9..16 (incl bias block).
// Per jb: GEMM 64x256 (K=160, 5 ks; B depth-1 register-prefetched from
// COALESCED frag-linear stream; A frag-linear in LDS, conflict-free), then
// register fold over jl with f32 h from LDS. Cross-wave reduce in LDS,
// plain coalesced stores into part[jy]. No atomics.
// ---------------------------------------------------------------------------
struct SmemT {
  unsigned short A[ABLK];        // 20,480 B (aliased by outr after compute)
  float hbuf[2][32 * OSTR];      // 2 x 8704 B : [p_l][jl*4+q]
};

__global__ __launch_bounds__(256, 2)
void ml_main(const unsigned short* __restrict__ Afrag,
             const unsigned short* __restrict__ Bfrag,
             const float* __restrict__ pos, const float* __restrict__ w1,
             const float* __restrict__ b1,
             float* __restrict__ part)
{
  __shared__ SmemT sm;
  const int tid  = threadIdx.x;
  const int lane = tid & 63;
  const int wid  = tid >> 6;
  const int bx   = blockIdx.x;       // 0..287
  const int jy   = blockIdx.y;       // 0..1
  const int p0   = bx * 32;
  const int jb0     = jy ? 9 : 0;
  const int jb_last = jy ? 16 : 8;

  // per-wave B base (frag-linear): wave reads at bwave + jb*BJB + ks*8192 + ni*512
  const unsigned short* bwave = Bfrag + wid * 2048 + lane * 8;

  // ---- stage A (frag-linear, pure linear copy) into LDS ----
  const unsigned short* Ablk = Afrag + (size_t)bx * ABLK;
  u16x8 av[5];
#pragma unroll
  for (int i = 0; i < 5; i++)
    av[i] = *(const u16x8*)(Ablk + (i * 256 + tid) * 8);

  // ---- per-thread pos values: p = p0 + (tid>>3), all 4 q ----
  float pv[4][3];
  {
    int p = p0 + (tid >> 3);
    int hh = p / 96, ww = p - hh * 96;
#pragma unroll
    for (int q = 0; q < 4; q++) {
      int m = hh * 384 + (q >> 1) * 192 + ww * 2 + (q & 1);
      pv[q][0] = pos[m * 3 + 0];
      pv[q][1] = pos[m * 3 + 1];
      pv[q][2] = pos[m * 3 + 2];
    }
  }

#pragma unroll
  for (int i = 0; i < 5; i++)
    *(u16x8*)(sm.A + (i * 256 + tid) * 8) = av[i];

  // ---- B prefetch buffers (named; parity handled at call sites) ----
  s16x8 br0[4], br1[4];
  {
    const unsigned short* bb = bwave + (size_t)jb0 * BJB;   // (jb0, ks=0)
#pragma unroll
    for (int ni = 0; ni < 4; ni++)
      br0[ni] = *(const s16x8*)(bb + ni * 512);
  }

  f32x4 oa[4][4];                    // [mi][reg] over q
#pragma unroll
  for (int mi = 0; mi < 4; mi++)
#pragma unroll
    for (int reg = 0; reg < 4; reg++) {
      f32x4 z = {0.f, 0.f, 0.f, 0.f};
      oa[mi][reg] = z;
    }

  __syncthreads();                   // A staged

  // jblock: bx0 holds (jb, ks=0); even ks compute bx0, odd bx1; the ks==4
  // prefetch of (jb+1, 0) lands in bx1 -> caller swaps for next jb.
  auto jblock = [&](int jb, s16x8 (&bx0)[4], s16x8 (&bx1)[4]) {
    // ---- hbuf[jb&1]: h[p][jl][q] f32 (bias block: jl==0 -> 1 else 0) ----
    {
      float* hb = sm.hbuf[jb & 1];
      int p_h = tid >> 3, sub = tid & 7;
#pragma unroll
      for (int t = 0; t < 2; t++) {
        int jl = sub + t * 8;
        f32x4 hv;
        if (jb < 16) {
          int j = jb * 16 + jl;
          float wa = w1[j], wb = w1[256 + j], wc = w1[512 + j], bb = b1[j];
#pragma unroll
          for (int q = 0; q < 4; q++) {
            float h = pv[q][0] * wa + pv[q][1] * wb + pv[q][2] * wc + bb;
            hv[q] = (h >= 0.f) ? h : 0.2f * h;
          }
        } else {
          float v = (jl == 0) ? 1.f : 0.f;
          hv[0] = v; hv[1] = v; hv[2] = v; hv[3] = v;
        }
        *(f32x4*)&hb[p_h * OSTR + jl * 4] = hv;
      }
    }
    __syncthreads();                 // hbuf visible (dbuf protects prev readers)

    // ---- GEMM 64 x 256, K=160 (5 steps), B global-direct prefetched ----
    f32x4 acc[4][4];
#pragma unroll
    for (int mi = 0; mi < 4; mi++)
#pragma unroll
      for (int ni = 0; ni < 4; ni++) {
        f32x4 z = {0.f, 0.f, 0.f, 0.f};
        acc[mi][ni] = z;
      }

#pragma unroll
    for (int ks = 0; ks < 5; ks++) {
      s16x8 (&bcur)[4]  = (ks & 1) ? bx1 : bx0;   // compile-time under unroll
      s16x8 (&bnext)[4] = (ks & 1) ? bx0 : bx1;
      if (!(jb == jb_last && ks == 4)) {
        int njb = (ks < 4) ? jb : jb + 1;
        int nks = (ks < 4) ? ks + 1 : 0;
        const unsigned short* bb = bwave + (size_t)njb * BJB + nks * 8192;
#pragma unroll
        for (int ni = 0; ni < 4; ni++)
          bnext[ni] = *(const s16x8*)(bb + ni * 512);
      }
      s16x8 af[4];
#pragma unroll
      for (int mi = 0; mi < 4; mi++)
        af[mi] = *(const s16x8*)(sm.A + (ks * 4 + mi) * 512 + lane * 8);
#pragma unroll
      for (int mi = 0; mi < 4; mi++)
#pragma unroll
        for (int ni = 0; ni < 4; ni++)
          acc[mi][ni] = __builtin_amdgcn_mfma_f32_16x16x32_bf16(af[mi], bcur[ni], acc[mi][ni], 0, 0, 0);
    }

    // ---- register fold over this j-block's 16 jl (wave owns jl = wid*4+ni) ----
    {
      const float* hb = sm.hbuf[jb & 1];
#pragma unroll
      for (int mi = 0; mi < 4; mi++) {
        int pb = mi * 8 + (lane >> 4) * 2;
#pragma unroll
        for (int ni = 0; ni < 4; ni++) {
          int jl = wid * 4 + ni;
          const float* hp = &hb[pb * OSTR + jl * 4];
          f32x4 h0 = *(const f32x4*)hp;
          f32x4 h1 = *(const f32x4*)(hp + OSTR);
          f32x4 a = acc[mi][ni];
          oa[mi][0] += h0 * a[0];
          oa[mi][1] += h0 * a[1];
          oa[mi][2] += h1 * a[2];
          oa[mi][3] += h1 * a[3];
        }
      }
    }
  };

  // j-blocks in parity pairs (5 ks per jb flips prefetch parity)
#pragma unroll 1
  for (int t = 0; t < 4; t++) {
    jblock(jb0 + 2 * t,     br0, br1);
    jblock(jb0 + 2 * t + 1, br1, br0);
  }
  if (!jy) jblock(8, br0, br1);      // jy=0 has 9 jb (0..8); jy=1 has 8 (9..16)

  // ---- cross-wave reduce of j-quarters (outr aliases A region) ----
  float* outr = (float*)sm.A;        // 64 x OSTR f32 = 17,408 B <= 20,480 B
  __syncthreads();                   // all compute done: A + hbuf dead
  if (wid == 0) {
#pragma unroll
    for (int mi = 0; mi < 4; mi++)
#pragma unroll
      for (int reg = 0; reg < 4; reg++) {
        int row = mi * 16 + (lane >> 4) * 4 + reg;
        *(f32x4*)&outr[row * OSTR + (lane & 15) * 4] = oa[mi][reg];
      }
  }
  __syncthreads();
#pragma unroll 1
  for (int r = 1; r < 4; r++) {
    if (wid == r) {
#pragma unroll
      for (int mi = 0; mi < 4; mi++)
#pragma unroll
        for (int reg = 0; reg < 4; reg++) {
          int row = mi * 16 + (lane >> 4) * 4 + reg;
          f32x4* dst = (f32x4*)&outr[row * OSTR + (lane & 15) * 4];
          *dst += oa[mi][reg];
        }
    }
    __syncthreads();
  }

  // ---- writeout: plain coalesced stores into part[jy] ([n2][c][y][x]) ----
  const int hh0 = bx / 3;            // p0/96
  const int ww0 = (bx - hh0 * 3) * 32;
  float* pdst = part + (size_t)jy * OUTSZ;
#pragma unroll 1
  for (int i = 0; i < 16; i++) {
    int flat = i * 256 + tid;        // 0..4095
    int xl = flat & 63;
    int si = (flat >> 6) & 1;
    int c  = (flat >> 7) & 15;
    int n2 = flat >> 11;
    int pl = xl >> 1, sj = xl & 1;
    int q = si * 2 + sj;
    int row = pl * 2 + n2;
    float v = outr[row * OSTR + c * 4 + q];
    pdst[((n2 * 16 + c) * 192 + hh0 * 2 + si) * 192 + ww0 * 2 + xl] = v;
  }
}

// ---------------------------------------------------------------------------
// reduce: out = part[0] + part[1], coalesced f32x4.
// ---------------------------------------------------------------------------
__global__ __launch_bounds__(256)
void ml_reduce(const float* __restrict__ part, float* __restrict__ out)
{
  int i = blockIdx.x * 256 + threadIdx.x;      // 0..294911
  size_t e = (size_t)i * 4;
  f32x4 s = *(const f32x4*)(part + e);
  s += *(const f32x4*)(part + OUTSZ + e);
  *(f32x4*)(out + e) = s;
}

// ---------------------------------------------------------------------------
extern "C" void kernel_launch(void* const* d_in, const int* in_sizes, int n_in,
                              void* d_out, int out_size, void* d_ws, size_t ws_size,
                              hipStream_t stream) {
  const float* x   = (const float*)d_in[0];
  const float* pos = (const float*)d_in[1];
  // d_in[2] = mask (all true) -- unused
  const float* w1  = (const float*)d_in[3];
  const float* b1  = (const float*)d_in[4];
  const float* w2  = (const float*)d_in[5];
  const float* b2  = (const float*)d_in[6];
  float* out = (float*)d_out;

  unsigned short* Afrag = (unsigned short*)d_ws;       // 288*10240*2 = 5,898,240 B
  unsigned short* Bfrag = Afrag + (size_t)288 * ABLK;  // 87040*8*2  = 1,392,640 B
  float* part = (float*)(Bfrag + (size_t)87040 * 8);   // 2*OUTSZ*4  = 9,437,184 B

  // prep: 368640 (A) + 87040 (B) = 455680 = 1780 * 256
  ml_prep<<<1780, 256, 0, stream>>>(x, w2, b2, Afrag, Bfrag);
  ml_main<<<dim3(288, 2), 256, 0, stream>>>(Afrag, Bfrag, pos, w1, b1, part);
  ml_reduce<<<1152, 256, 0, stream>>>(part, out);
}

// Round 10
// 84.130 us; speedup vs baseline: 2.4376x; 2.4376x over previous
//
#include <hip/hip_runtime.h>
#include <stdint.h>

typedef __attribute__((ext_vector_type(8))) short          s16x8;
typedef __attribute__((ext_vector_type(8))) unsigned short u16x8;
typedef __attribute__((ext_vector_type(4))) float          f32x4;

#define HWPIX 9216
#define OSTR  68            // padded hbuf/outr row stride (f32)
#define ABLK  10240         // u16 per block's A-frag region: 5ks*4mi*64lane*8

static __device__ __forceinline__ unsigned short f2bf(float f) {
  unsigned int u = __float_as_uint(f);
  u += 0x7fffu + ((u >> 16) & 1u);
  return (unsigned short)(u >> 16);
}

// ---------------------------------------------------------------------------
// prep: A and B in FRAGMENT-LINEAR order (consumer lane l reads base + l*16B).
// A-frag: [bx(288)][ks(5)][mi(4)][lane(64)][8 u16]
//   row = bx*64 + mi*16 + (lane&15) (= p*2+n2), k = ks*32 + (lane>>4)*8 + t
// B-frag: [jb(17)][ks(5)][wid(4)][ni(4)][lane(64)][8 u16]
//   col = jb*256 + wid*64 + ni*16 + (lane&15) (col<4096: j*16+c),
//   k   = ks*32 + (lane>>4)*8 + t
//   jb==16 = bias block: col 4096+c for jl==0 -> b2[k*16+c], else 0.
// ---------------------------------------------------------------------------
__global__ __launch_bounds__(256)
void ml_prep(const float* __restrict__ x, const float* __restrict__ w2,
             const float* __restrict__ b2,
             unsigned short* __restrict__ Afrag, unsigned short* __restrict__ Bfrag)
{
  int idx = blockIdx.x * 256 + threadIdx.x;
  if (idx < 368640) {                      // A: 288 blocks x 1280 u16x8 units
    int bx = idx / 1280, r = idx - bx * 1280;
    int ks = r >> 8, mi = (r >> 6) & 3, lane = r & 63;
    int row = bx * 64 + mi * 16 + (lane & 15);
    int p = row >> 1, n2 = row & 1;
    int hh = p / 96, ww = p - hh * 96;
    int k0 = ks * 32 + (lane >> 4) * 8;
    u16x8 v;
#pragma unroll
    for (int t = 0; t < 8; t++) {
      int k = k0 + t;
      float xv = 0.f;
      if (k < 144) {
        int cc = k / 9, kidx = k - cc * 9;
        int ih = hh + kidx / 3 - 1, iw = ww + (kidx % 3) - 1;
        if (ih >= 0 && ih < 96 && iw >= 0 && iw < 96)
          xv = x[((n2 * 16 + cc) * 96 + ih) * 96 + iw];
      }
      v[t] = f2bf(xv);
    }
    *(u16x8*)(Afrag + (size_t)idx * 8) = v;
    return;
  }
  idx -= 368640;
  if (idx < 87040) {                       // B: 17jb*5ks*4wid*4ni*64lane units
    int lane = idx & 63;
    int u  = idx >> 6;
    int ni = u & 3;
    int u2 = u >> 2;
    int wid = u2 & 3;
    int u3 = u2 >> 2;
    int ks = u3 % 5;
    int jb = u3 / 5;
    int col = jb * 256 + wid * 64 + ni * 16 + (lane & 15);
    int k0 = ks * 32 + (lane >> 4) * 8;
    u16x8 v;
    if (col < 4096) {
      int j = col >> 4, c = col & 15;
#pragma unroll
      for (int t = 0; t < 8; t++) {
        int k = k0 + t;
        v[t] = (k < 144) ? f2bf(w2[j * 2304 + k * 16 + c]) : (unsigned short)0;
      }
    } else {
      int m = col - 4096;
      int jl = m >> 4, c = m & 15;
#pragma unroll
      for (int t = 0; t < 8; t++) {
        int k = k0 + t;
        v[t] = (jl == 0 && k < 144) ? f2bf(b2[k * 16 + c]) : (unsigned short)0;
      }
    }
    *(u16x8*)(Bfrag + (size_t)idx * 8) = v;
  }
}

// ---------------------------------------------------------------------------
// main: grid(288), 512 threads (8 waves = 2 waves/SIMD). Block = 64 M-rows
// (32 p x 2 n2) x ALL 4352 N-cols. Waves: wni = wid&3 (ni quarter),
// wjb = wid>>2 (j parity). Step s (0..8): wave processes jb = 2s+wjb
// (wjb=1 idle at s=8). Per step: GEMM 64x64/wave (K=160, 5 ks, B
// register-prefetched depth-1 from COALESCED frag-linear stream; A
// frag-linear in LDS, conflict-free), then register fold over jl with f32
// h from LDS. Two-tree cross-wave reduce in LDS, plain coalesced stores
// to out. No atomics, no partials, no reduce kernel.
// ---------------------------------------------------------------------------
struct SmemT {
  unsigned short A[ABLK];          // 20,480 B (aliased by outr after compute)
  float hbuf[2][2][32 * OSTR];     // dbuf x wjb x [p][jl*4+q] = 34,816 B (aliased by outr2)
};

__global__ __launch_bounds__(512, 2)
void ml_main(const unsigned short* __restrict__ Afrag,
             const unsigned short* __restrict__ Bfrag,
             const float* __restrict__ pos, const float* __restrict__ w1,
             const float* __restrict__ b1,
             float* __restrict__ out)
{
  __shared__ SmemT sm;
  const int tid  = threadIdx.x;
  const int lane = tid & 63;
  const int wid  = tid >> 6;
  const int wni  = wid & 3;
  const int wjb  = wid >> 2;
  const int bx   = blockIdx.x;       // 0..287
  const int p0   = bx * 32;

  // per-wave B base (frag-linear): load addr = bwv + (jb*5+ks)*8192 + ni*512
  const unsigned short* bwv = Bfrag + wni * 2048 + lane * 8;

  // ---- stage A (frag-linear, pure linear copy) into LDS ----
  const unsigned short* Ablk = Afrag + (size_t)bx * ABLK;
  u16x8 av[3];
#pragma unroll
  for (int i = 0; i < 3; i++) {
    int aid = i * 512 + tid;
    if (aid < 1280) av[i] = *(const u16x8*)(Ablk + aid * 8);
  }

  // ---- per-thread pos values: p = p0 + (tid>>4), all 4 q ----
  float pv[4][3];
  {
    int p = p0 + (tid >> 4);
    int hh = p / 96, ww = p - hh * 96;
#pragma unroll
    for (int q = 0; q < 4; q++) {
      int m = hh * 384 + (q >> 1) * 192 + ww * 2 + (q & 1);
      pv[q][0] = pos[m * 3 + 0];
      pv[q][1] = pos[m * 3 + 1];
      pv[q][2] = pos[m * 3 + 2];
    }
  }

#pragma unroll
  for (int i = 0; i < 3; i++) {
    int aid = i * 512 + tid;
    if (aid < 1280) *(u16x8*)(sm.A + aid * 8) = av[i];
  }

  // ---- initial B prefetch: (jb = wjb, ks = 0) ----
  s16x8 br0[4], br1[4];
  {
    const unsigned short* bb = bwv + wjb * 5 * 8192;
#pragma unroll
    for (int ni = 0; ni < 4; ni++)
      br0[ni] = *(const s16x8*)(bb + ni * 512);
  }

  f32x4 oa[4][4];                    // [mi][reg] over q
#pragma unroll
  for (int mi = 0; mi < 4; mi++)
#pragma unroll
    for (int reg = 0; reg < 4; reg++) {
      f32x4 z = {0.f, 0.f, 0.f, 0.f};
      oa[mi][reg] = z;
    }

  __syncthreads();                   // A staged

  // step s: bx0 holds (jb_w, ks=0); 5 ks flip parity; ks==4 prefetches
  // (jb_w+2, 0) into bx1 -> caller swaps buffers per step.
  auto step = [&](int s, s16x8 (&bx0)[4], s16x8 (&bx1)[4]) {
    // ---- hbuf[s&1][wj]: h[p][jl][q] f32; thread = (p=tid>>4, jl=tid&15) ----
    {
      int p_h = tid >> 4, jl = tid & 15;
#pragma unroll
      for (int wj = 0; wj < 2; wj++) {
        int jb = 2 * s + wj;
        if (jb <= 16) {
          f32x4 hv;
          if (jb < 16) {
            int j = jb * 16 + jl;
            float wa = w1[j], wb = w1[256 + j], wc = w1[512 + j], bb = b1[j];
#pragma unroll
            for (int q = 0; q < 4; q++) {
              float h = pv[q][0] * wa + pv[q][1] * wb + pv[q][2] * wc + bb;
              hv[q] = (h >= 0.f) ? h : 0.2f * h;
            }
          } else {
            float v = (jl == 0) ? 1.f : 0.f;
            hv[0] = v; hv[1] = v; hv[2] = v; hv[3] = v;
          }
          *(f32x4*)&sm.hbuf[s & 1][wj][p_h * OSTR + jl * 4] = hv;
        }
      }
    }
    __syncthreads();                 // hbuf visible (dbuf protects prev readers)

    const int jb_w = 2 * s + wjb;
    if (jb_w <= 16) {                // wave-uniform
      // ---- GEMM 64x64 per wave, K=160 (5 ks), B depth-1 prefetched ----
      f32x4 acc[4][4];
#pragma unroll
      for (int mi = 0; mi < 4; mi++)
#pragma unroll
        for (int ni = 0; ni < 4; ni++) {
          f32x4 z = {0.f, 0.f, 0.f, 0.f};
          acc[mi][ni] = z;
        }

#pragma unroll
      for (int ks = 0; ks < 5; ks++) {
        s16x8 (&bcur)[4]  = (ks & 1) ? bx1 : bx0;   // compile-time under unroll
        s16x8 (&bnext)[4] = (ks & 1) ? bx0 : bx1;
        if (ks < 4 || jb_w + 2 <= 16) {
          int njb = (ks < 4) ? jb_w : jb_w + 2;
          int nks = (ks < 4) ? ks + 1 : 0;
          const unsigned short* bb = bwv + (njb * 5 + nks) * 8192;
#pragma unroll
          for (int ni = 0; ni < 4; ni++)
            bnext[ni] = *(const s16x8*)(bb + ni * 512);
        }
        s16x8 af[4];
#pragma unroll
        for (int mi = 0; mi < 4; mi++)
          af[mi] = *(const s16x8*)(sm.A + (ks * 4 + mi) * 512 + lane * 8);
#pragma unroll
        for (int mi = 0; mi < 4; mi++)
#pragma unroll
          for (int ni = 0; ni < 4; ni++)
            acc[mi][ni] = __builtin_amdgcn_mfma_f32_16x16x32_bf16(af[mi], bcur[ni], acc[mi][ni], 0, 0, 0);
      }

      // ---- register fold over 16 jl (this wave owns jl = wni*4+ni) ----
      const float* hb = &sm.hbuf[s & 1][wjb][0];
#pragma unroll
      for (int mi = 0; mi < 4; mi++) {
        int pb = mi * 8 + (lane >> 4) * 2;
#pragma unroll
        for (int ni = 0; ni < 4; ni++) {
          int jl = wni * 4 + ni;
          const float* hp = &hb[pb * OSTR + jl * 4];
          f32x4 h0 = *(const f32x4*)hp;
          f32x4 h1 = *(const f32x4*)(hp + OSTR);
          f32x4 a = acc[mi][ni];
          oa[mi][0] += h0 * a[0];
          oa[mi][1] += h0 * a[1];
          oa[mi][2] += h1 * a[2];
          oa[mi][3] += h1 * a[3];
        }
      }
    }
  };

  // 9 steps: 4 parity pairs + final even step (5 ks/step flips parity)
#pragma unroll 1
  for (int s2 = 0; s2 < 4; s2++) {
    step(2 * s2,     br0, br1);
    step(2 * s2 + 1, br1, br0);
  }
  step(8, br0, br1);

  // ---- cross-wave reduce: waves 0-3 -> outr, waves 4-7 -> outr2 ----
  float* outr  = (float*)sm.A;          // 64 x OSTR f32 = 17,408 B <= 20,480 B
  float* outr2 = (float*)&sm.hbuf[0][0][0];   // 17,408 B <= 34,816 B
  __syncthreads();                      // all compute done: A + hbuf dead
  if (wid == 0 || wid == 4) {
    float* dst = (wid == 0) ? outr : outr2;
#pragma unroll
    for (int mi = 0; mi < 4; mi++)
#pragma unroll
      for (int reg = 0; reg < 4; reg++) {
        int row = mi * 16 + (lane >> 4) * 4 + reg;
        *(f32x4*)&dst[row * OSTR + (lane & 15) * 4] = oa[mi][reg];
      }
  }
  __syncthreads();
#pragma unroll 1
  for (int r = 1; r < 4; r++) {
    if (wid == r || wid == r + 4) {
      float* dst = (wid == r) ? outr : outr2;
#pragma unroll
      for (int mi = 0; mi < 4; mi++)
#pragma unroll
        for (int reg = 0; reg < 4; reg++) {
          int row = mi * 16 + (lane >> 4) * 4 + reg;
          f32x4* d = (f32x4*)&dst[row * OSTR + (lane & 15) * 4];
          *d += oa[mi][reg];
        }
    }
    __syncthreads();
  }

  // ---- writeout: [n2][c][y][x], 64 contiguous f32 per segment, plain ----
  const int hh0 = bx / 3;            // p0/96
  const int ww0 = (bx - hh0 * 3) * 32;
#pragma unroll 1
  for (int i = 0; i < 8; i++) {
    int flat = i * 512 + tid;        // 0..4095
    int xl = flat & 63;
    int si = (flat >> 6) & 1;
    int c  = (flat >> 7) & 15;
    int n2 = flat >> 11;
    int pl = xl >> 1, sj = xl & 1;
    int q = si * 2 + sj;
    int row = pl * 2 + n2;
    int idx = row * OSTR + c * 4 + q;
    float v = outr[idx] + outr2[idx];
    out[((n2 * 16 + c) * 192 + hh0 * 2 + si) * 192 + ww0 * 2 + xl] = v;
  }
}

// ---------------------------------------------------------------------------
extern "C" void kernel_launch(void* const* d_in, const int* in_sizes, int n_in,
                              void* d_out, int out_size, void* d_ws, size_t ws_size,
                              hipStream_t stream) {
  const float* x   = (const float*)d_in[0];
  const float* pos = (const float*)d_in[1];
  // d_in[2] = mask (all true) -- unused
  const float* w1  = (const float*)d_in[3];
  const float* b1  = (const float*)d_in[4];
  const float* w2  = (const float*)d_in[5];
  const float* b2  = (const float*)d_in[6];
  float* out = (float*)d_out;

  unsigned short* Afrag = (unsigned short*)d_ws;       // 288*10240*2 = 5,898,240 B
  unsigned short* Bfrag = Afrag + (size_t)288 * ABLK;  // 87040*8*2  = 1,392,640 B

  // prep: 368640 (A) + 87040 (B) = 455680 = 1780 * 256
  ml_prep<<<1780, 256, 0, stream>>>(x, w2, b2, Afrag, Bfrag);
  ml_main<<<288, 512, 0, stream>>>(Afrag, Bfrag, pos, w1, b1, out);
}